// Round 10
// baseline (3873.913 us; speedup 1.0000x reference)
//
#include <hip/hip_runtime.h>
#include <math.h>

// Problem constants (fixed by reference).
#define HIDDEN 1024
#define MEL    80
#define TSTEPS 1000
#define BATCH  64

// R10 = R7 structure + distributed tail + agent-scope exchange.
// 64 persistent blocks x 1024 threads (16 waves). Block owns 16 hidden units.
// Wave wv: columns [64wv, 64wv+64) for all 64 gate rows (MAC phase), AND the
// full tail (reduce+gates+publish) for unit wv (tail phase). Lane = gate row
// in MAC, (gate,chunk) in tail. Exchange: packed {tag:32|float:32} 8B relaxed
// AGENT-scope atomics (m20: agent scope is cross-XCD correct), double-buffered.
#define NBLK 64
#define TPB  1024

typedef unsigned long long ull;

// v_exp_f32-based activations (abs err ~1e-6 << 8.3e-4 threshold).
__device__ __forceinline__ float sigm_f(float x) { return 1.0f / (1.0f + __expf(-x)); }
__device__ __forceinline__ float tanh_f(float x) { return 1.0f - 2.0f / (1.0f + __expf(2.0f * x)); }

__global__ __launch_bounds__(TPB, 4) void tts_recur(
    const float* __restrict__ dec_Wih,   // [4096, 80]
    const float* __restrict__ dec_Whh,   // [4096, 1024]
    const float* __restrict__ dec_bih,   // [4096]
    const float* __restrict__ dec_bhh,   // [4096]
    const float* __restrict__ lin_W,     // [80, 1024]
    const float* __restrict__ lin_b,     // [80]
    float* __restrict__ h_hist,          // [TSTEPS, 1024] (for epilogue)
    ull* __restrict__ hbuf)              // [2, 1024] packed {tag:32|float:32}
{
    const int tid  = threadIdx.x;
    const int blk  = blockIdx.x;
    const int wv   = tid >> 6;           // 0..15: column slice / owned unit
    const int lane = tid & 63;           // gate row (MAC); (gate,chunk) in tail
    const int jj   = lane & 15;          // unit within block (fold phase)
    const int gate = lane >> 4;          // i,f,g,o
    const int row_g  = gate * HIDDEN + blk * 16 + jj;

    __shared__ __align__(16) float hEx[16][64];   // per-wave h slice (wave-private)
    __shared__ float part[2][64 * 17];            // partials, pitch 17 (2-way = free)

    // ---- one-time fold: w = Whh_row_slice + Wih_row @ lin_W_slice (regs) ----
    const float* wih = dec_Wih + (size_t)row_g * MEL;
    const float* whh = dec_Whh + (size_t)row_g * HIDDEN + wv * 64;
    float4 w[16];
#pragma unroll
    for (int k = 0; k < 16; ++k)
        w[k] = *(const float4*)(whh + k * 4);
#pragma unroll 1
    for (int m = 0; m < MEL; ++m) {
        const float aw = wih[m];
        const float4* lw4 = (const float4*)(lin_W + (size_t)m * HIDDEN + wv * 64);
#pragma unroll
        for (int k = 0; k < 8; ++k) {
            const float4 lw = lw4[k];
            w[k].x = fmaf(aw, lw.x, w[k].x); w[k].y = fmaf(aw, lw.y, w[k].y);
            w[k].z = fmaf(aw, lw.z, w[k].z); w[k].w = fmaf(aw, lw.w, w[k].w);
        }
#pragma unroll
        for (int k = 8; k < 16; ++k) {
            const float4 lw = lw4[k];
            w[k].x = fmaf(aw, lw.x, w[k].x); w[k].y = fmaf(aw, lw.y, w[k].y);
            w[k].z = fmaf(aw, lw.z, w[k].z); w[k].w = fmaf(aw, lw.w, w[k].w);
        }
    }
    float b_comb_r = dec_bih[row_g] + dec_bhh[row_g];
    const float b_dec_r = b_comb_r;                  // step 0 (x=0, no lin_b fold)
    for (int m = 0; m < MEL; ++m)
        b_comb_r = fmaf(wih[m], lin_b[m], b_comb_r);

    // Cell state of unit (blk*16 + wv), replicated across wave wv's lanes.
    float c_prev;

    // ---- step 0: g = b_dec (h=c=x=0); every wave does its own unit ----
    {
        // lane needs b_dec of (gate(lane), unit wv): held by lane 16*gate + wv.
        const float bdw = __shfl(b_dec_r, (lane & 48) + wv, 64);
        const float gi = __shfl(bdw, 0, 64);
        const float gg = __shfl(bdw, 32, 64);
        const float go = __shfl(bdw, 48, 64);
        const float c  = sigm_f(gi) * tanh_f(gg);    // f-gate * c0 = 0
        const float h  = sigm_f(go) * tanh_f(c);
        c_prev = c;
        if (lane == 0) {
            const ull pk = ((ull)1u << 32) | (ull)__float_as_uint(h);
            __hip_atomic_store(hbuf + blk * 16 + wv, pk,
                               __ATOMIC_RELAXED, __HIP_MEMORY_SCOPE_AGENT);
            h_hist[blk * 16 + wv] = h;
        }
    }

    // ---- steps 1..TSTEPS-1 ----
    for (int t = 1; t < TSTEPS; ++t) {
        const int buf = t & 1;
        // Poll own slot (tag==t valid); tag travels with value in one 8B atomic.
        {
            const ull* src = hbuf + ((t - 1) & 1) * HIDDEN;
            ull v = __hip_atomic_load(src + tid, __ATOMIC_RELAXED, __HIP_MEMORY_SCOPE_AGENT);
            while ((unsigned)(v >> 32) != (unsigned)t)
                v = __hip_atomic_load(src + tid, __ATOMIC_RELAXED, __HIP_MEMORY_SCOPE_AGENT);
            hEx[wv][lane] = __uint_as_float((unsigned)v);
        }
        __builtin_amdgcn_wave_barrier();   // per-wave DS order is HW-guaranteed

        // Broadcast MAC: 16 uniform-address ds_read_b128 + 64 fma, 4 accs.
        const float4* hp = (const float4*)&hEx[wv][0];
        float a0 = 0.f, a1 = 0.f, a2 = 0.f, a3 = 0.f;
#pragma unroll
        for (int k = 0; k < 16; k += 4) {
            const float4 h0 = hp[k], h1 = hp[k + 1], h2 = hp[k + 2], h3 = hp[k + 3];
            a0 = fmaf(w[k].x, h0.x, a0);   a0 = fmaf(w[k].y, h0.y, a0);
            a0 = fmaf(w[k].z, h0.z, a0);   a0 = fmaf(w[k].w, h0.w, a0);
            a1 = fmaf(w[k+1].x, h1.x, a1); a1 = fmaf(w[k+1].y, h1.y, a1);
            a1 = fmaf(w[k+1].z, h1.z, a1); a1 = fmaf(w[k+1].w, h1.w, a1);
            a2 = fmaf(w[k+2].x, h2.x, a2); a2 = fmaf(w[k+2].y, h2.y, a2);
            a2 = fmaf(w[k+2].z, h2.z, a2); a2 = fmaf(w[k+2].w, h2.w, a2);
            a3 = fmaf(w[k+3].x, h3.x, a3); a3 = fmaf(w[k+3].y, h3.y, a3);
            a3 = fmaf(w[k+3].z, h3.z, a3); a3 = fmaf(w[k+3].w, h3.w, a3);
        }
        part[buf][lane * 17 + wv] = (a0 + a1) + (a2 + a3);
        __syncthreads();                               // barrier B (one/step)

        // ---- distributed tail: wave wv finishes unit wv ----
        // lane = (gate g = lane>>4, chunk cc = lane&15); read partial of
        // (row 16g+wv, chunk cc): addr (16g+wv)*17+cc -> banks 2-way (free).
        {
            float s = part[buf][((lane & 48) + wv) * 17 + (lane & 15)];
            s += __shfl_xor(s, 1, 64);
            s += __shfl_xor(s, 2, 64);
            s += __shfl_xor(s, 4, 64);
            s += __shfl_xor(s, 8, 64);     // every lane in group g: full row sum
            const float gpre = s + __shfl(b_comb_r, (lane & 48) + wv, 64);
            const float gi = __shfl(gpre, 0, 64);
            const float gf = __shfl(gpre, 16, 64);
            const float gg = __shfl(gpre, 32, 64);
            const float go = __shfl(gpre, 48, 64);
            const float c  = sigm_f(gf) * c_prev + sigm_f(gi) * tanh_f(gg);
            const float h  = sigm_f(go) * tanh_f(c);
            c_prev = c;
            if (lane == 0) {
                const ull pk = ((ull)(unsigned)(t + 1) << 32) | (ull)__float_as_uint(h);
                __hip_atomic_store(hbuf + buf * HIDDEN + blk * 16 + wv, pk,
                                   __ATOMIC_RELAXED, __HIP_MEMORY_SCOPE_AGENT);
                h_hist[(size_t)t * HIDDEN + blk * 16 + wv] = h;
            }
        }
        // Race-freedom: part double-buffered (writes at t+1 hit part[buf^1],
        // readers of part[buf] pass B(t) first). hEx wave-private. hbuf
        // overwrite: wave publishes h(t) only after barrier B(t), which joins
        // the whole block's polls of h(t-1) -> every block had published
        // h(t-1) -> every block had fully consumed h(t-2) (R7 proof).
    }
}

// Epilogue: frame[t] = lin_W @ h[t] + lin_b, broadcast to 64 batch rows.
__global__ __launch_bounds__(128) void tts_frames(
    const float* __restrict__ lin_W, const float* __restrict__ lin_b,
    const float* __restrict__ h_hist, float* __restrict__ out)
{
    const int t = blockIdx.x;
    const int tid = threadIdx.x;
    __shared__ __align__(16) float h_sh[HIDDEN];
    __shared__ float f_s[MEL];
    const float4* src = (const float4*)(h_hist + (size_t)t * HIDDEN);
    ((float4*)h_sh)[tid] = src[tid];
    ((float4*)h_sh)[tid + 128] = src[tid + 128];
    __syncthreads();
    if (tid < MEL) {
        const float* wrow = lin_W + (size_t)tid * HIDDEN;
        float acc = lin_b[tid];
#pragma unroll 8
        for (int cc = 0; cc < HIDDEN; ++cc)
            acc = fmaf(wrow[cc], h_sh[cc], acc);
        f_s[tid] = acc;
    }
    __syncthreads();
    for (int idx = tid; idx < BATCH * MEL; idx += 128) {
        const int b = idx / MEL;
        const int m = idx - b * MEL;
        out[(size_t)b * TSTEPS * MEL + (size_t)t * MEL + m] = f_s[m];
    }
}

extern "C" void kernel_launch(void* const* d_in, const int* in_sizes, int n_in,
                              void* d_out, int out_size, void* d_ws, size_t ws_size,
                              hipStream_t stream) {
    // Inputs: 0 text, 1 text_lens, 2 max_audio_len, 3 W_emb, 4..7 enc_*,
    // 8..11 dec_{Wih,Whh,bih,bhh}, 12 lin_W, 13 lin_b. Encoder is dead code.
    const float* dec_Wih = (const float*)d_in[8];
    const float* dec_Whh = (const float*)d_in[9];
    const float* dec_bih = (const float*)d_in[10];
    const float* dec_bhh = (const float*)d_in[11];
    const float* lin_W   = (const float*)d_in[12];
    const float* lin_b   = (const float*)d_in[13];
    float* out = (float*)d_out;

    // Workspace: h_hist fp32 [1000][1024] (4,096,000 B) + hbuf [2][1024] ull.
    // 0xAA poison -> tag 0xAAAAAAAA never matches 1..1000, so no init pass.
    float* h_hist = (float*)d_ws;
    ull* hbuf = (ull*)((char*)d_ws + (size_t)TSTEPS * HIDDEN * sizeof(float));

    hipLaunchKernelGGL(tts_recur, dim3(NBLK), dim3(TPB), 0, stream,
                       dec_Wih, dec_Whh, dec_bih, dec_bhh, lin_W, lin_b, h_hist, hbuf);
    hipLaunchKernelGGL(tts_frames, dim3(TSTEPS), dim3(128), 0, stream,
                       lin_W, lin_b, h_hist, out);
}